// Round 1
// baseline (326.498 us; speedup 1.0000x reference)
//
#include <hip/hip_runtime.h>

#define NPTS 65536

// ---------------- Kernel 1: pack/transpose feature -> featT[N][128] ----------
__global__ __launch_bounds__(256) void k_pack(const float* __restrict__ spa,
                                              const float* __restrict__ spe,
                                              float* __restrict__ featT) {
    __shared__ float tile[64][129];
    const int n0 = blockIdx.x * 64;
    const int t = threadIdx.x;
    {
        const int p = t & 63;       // point offset: lanes contiguous -> coalesced
        const int c0 = t >> 6;      // wave id 0..3
        #pragma unroll
        for (int i = 0; i < 32; ++i) {
            const int c = c0 + (i << 2);            // 0..127
            const float v = (c < 64) ? spa[c * NPTS + n0 + p]
                                     : spe[(c - 64) * NPTS + n0 + p];
            tile[p][c] = v;                         // stride 129 -> 2-way (free)
        }
    }
    __syncthreads();
    {
        const int c = t & 127;
        const int p0 = t >> 7;
        #pragma unroll
        for (int i = 0; i < 32; ++i) {
            const int p = p0 + (i << 1);
            featT[(size_t)(n0 + p) * 128 + c] = tile[p][c];  // coalesced 512B rows
        }
    }
}

// ---------------- Kernel 2: M = WQ^T * WK for both attentions ----------------
__global__ __launch_bounds__(256) void k_matM(const float* __restrict__ WQa,
                                              const float* __restrict__ WKa,
                                              const float* __restrict__ WQe,
                                              const float* __restrict__ WKe,
                                              float* __restrict__ M) {
    const int t = threadIdx.x;
    for (int i = 0; i < 32; ++i) {
        const int id = t + (i << 8);      // 0..8191
        const int which = id >> 12;       // 0: spa, 1: spe
        const int c = (id >> 6) & 63;
        const int e = id & 63;
        const float* WQ = which ? WQe : WQa;
        const float* WK = which ? WKe : WKa;
        float acc = 0.f;
        #pragma unroll
        for (int d = 0; d < 64; ++d) acc += WQ[d * 64 + c] * WK[d * 64 + e];
        M[id] = acc;                      // M[which][c][e]
    }
}

// ---------------- Kernel 3: qeff[n][e'] = sum_c q[c] * M[c][e'] --------------
__global__ __launch_bounds__(256) void k_qeff(const float* __restrict__ featT,
                                              const float* __restrict__ M,
                                              float* __restrict__ qeff) {
    __shared__ float ftile[64][132];   // stride 132 -> 16B-aligned rows
    const int n0 = blockIdx.x * 64;
    const int t = threadIdx.x;
    {
        const int c = t & 127;
        const int p0 = t >> 7;
        #pragma unroll
        for (int i = 0; i < 32; ++i) {
            const int p = p0 + (i << 1);
            ftile[p][c] = featT[(size_t)(n0 + p) * 128 + c];
        }
    }
    const int ec = t & 127;            // output channel
    const int which = ec >> 6;         // 0: qeff_spa (from spa half), 1: qeff_spe
    const int e = ec & 63;
    float mcol[64];
    #pragma unroll
    for (int cc = 0; cc < 64; ++cc) mcol[cc] = M[which * 4096 + cc * 64 + e]; // coalesced
    __syncthreads();
    const int p0 = t >> 7;
    for (int i = 0; i < 32; ++i) {
        const int p = p0 + (i << 1);
        const float4* fr = reinterpret_cast<const float4*>(&ftile[p][which << 6]); // uniform -> broadcast
        float acc = 0.f;
        #pragma unroll
        for (int c4 = 0; c4 < 16; ++c4) {
            const float4 v = fr[c4];
            acc += v.x * mcol[4*c4] + v.y * mcol[4*c4+1] + v.z * mcol[4*c4+2] + v.w * mcol[4*c4+3];
        }
        qeff[(size_t)(n0 + p) * 128 + ec] = acc;
    }
}

// ---------------- Kernel 4: attention (1 wave = 1 point) ---------------------
__global__ __launch_bounds__(256) void k_attn(const float* __restrict__ featT,
                                              const float* __restrict__ qeff,
                                              const int* __restrict__ idx,
                                              float* __restrict__ sT) {
    const int wave = threadIdx.x >> 6;
    const int lane = threadIdx.x & 63;
    const int n = blockIdx.x * 4 + wave;

    const float qa = qeff[(size_t)n * 128 + lane];        // qeff_spa, lane=channel e
    const float qe = qeff[(size_t)n * 128 + 64 + lane];   // qeff_spe
    const int jv = idx[n * 16 + (lane & 15)];             // lane k holds neighbor k

    float xa[16], xe[16], sa[16], se[16];
    #pragma unroll
    for (int k = 0; k < 16; ++k) {
        const int j = __shfl(jv, k);
        const float* fj = &featT[(size_t)j * 128];
        xa[k] = fj[lane];        // spa half of neighbor
        xe[k] = fj[64 + lane];   // spe half of neighbor
        float pa = qa * xe[k];   // spa attention keys come from spe half
        float pe = qe * xa[k];   // spe attention keys come from spa half
        #pragma unroll
        for (int m = 1; m < 64; m <<= 1) {
            pa += __shfl_xor(pa, m);
            pe += __shfl_xor(pe, m);
        }
        sa[k] = pa * 0.125f;     // / sqrt(64)
        se[k] = pe * 0.125f;
    }
    // softmax over 16 (uniform across lanes after butterfly)
    float ma = sa[0], me = se[0];
    #pragma unroll
    for (int k = 1; k < 16; ++k) { ma = fmaxf(ma, sa[k]); me = fmaxf(me, se[k]); }
    float da = 0.f, de = 0.f;
    #pragma unroll
    for (int k = 0; k < 16; ++k) {
        sa[k] = __expf(sa[k] - ma); da += sa[k];
        se[k] = __expf(se[k] - me); de += se[k];
    }
    const float ra = 1.f / da, re = 1.f / de;
    float accA = 0.f, accE = 0.f;
    #pragma unroll
    for (int k = 0; k < 16; ++k) {
        accA += sa[k] * xe[k];   // weighted raw spe sum (for WV_spa later)
        accE += se[k] * xa[k];   // weighted raw spa sum (for WV_spe later)
    }
    sT[(size_t)n * 128 + lane] = accA * ra;
    sT[(size_t)n * 128 + 64 + lane] = accE * re;
}

// ---------------- Kernel 5: ctx = WV*s + b, residual, transpose-write --------
__global__ __launch_bounds__(256) void k_out(const float* __restrict__ sT,
                                             const float* __restrict__ spa,
                                             const float* __restrict__ spe,
                                             const float* __restrict__ WVa,
                                             const float* __restrict__ bVa,
                                             const float* __restrict__ WVe,
                                             const float* __restrict__ bVe,
                                             float* __restrict__ out) {
    __shared__ float stile[64][132];
    __shared__ float wv[2][64][65];
    const int n0 = blockIdx.x * 64;
    const int t = threadIdx.x;
    {
        const int c = t & 127;
        const int p0 = t >> 7;
        #pragma unroll
        for (int i = 0; i < 32; ++i) {
            const int p = p0 + (i << 1);
            stile[p][c] = sT[(size_t)(n0 + p) * 128 + c];
        }
    }
    {
        #pragma unroll
        for (int i = 0; i < 32; ++i) {
            const int id = t + (i << 8);
            const int w = id >> 12;
            const int dd = (id >> 6) & 63;
            const int e = id & 63;
            wv[w][dd][e] = (w ? WVe : WVa)[dd * 64 + e];   // coalesced stage
        }
    }
    __syncthreads();
    const int d = t & 127;            // output channel
    const int which = d >> 6;
    const int dd = d & 63;
    float wrow[64];
    #pragma unroll
    for (int e = 0; e < 64; ++e) wrow[e] = wv[which][dd][e];  // 2-way (free)
    const float bias = which ? bVe[dd] : bVa[dd];
    const int p0 = t >> 7;
    float acc[32];
    #pragma unroll
    for (int i = 0; i < 32; ++i) {
        const int p = p0 + (i << 1);
        const float4* sr = reinterpret_cast<const float4*>(&stile[p][which << 6]); // uniform
        float a = bias;
        #pragma unroll
        for (int e4 = 0; e4 < 16; ++e4) {
            const float4 v = sr[e4];
            a += v.x * wrow[4*e4] + v.y * wrow[4*e4+1] + v.z * wrow[4*e4+2] + v.w * wrow[4*e4+3];
        }
        acc[i] = a;
    }
    __syncthreads();
    #pragma unroll
    for (int i = 0; i < 32; ++i) {
        const int p = p0 + (i << 1);
        stile[p][d] = acc[i];         // reuse stile as ctx tile
    }
    __syncthreads();
    {
        const int p = t & 63;
        const int d0 = t >> 6;
        #pragma unroll
        for (int i = 0; i < 32; ++i) {
            const int ch = d0 + (i << 2);
            const float f = (ch < 64) ? spa[ch * NPTS + n0 + p]
                                      : spe[(ch - 64) * NPTS + n0 + p];
            out[(size_t)ch * NPTS + n0 + p] = f + stile[p][ch];
        }
    }
}

extern "C" void kernel_launch(void* const* d_in, const int* in_sizes, int n_in,
                              void* d_out, int out_size, void* d_ws, size_t ws_size,
                              hipStream_t stream) {
    const float* spa = (const float*)d_in[0];
    const float* spe = (const float*)d_in[1];
    const int* idx   = (const int*)d_in[2];
    const float* WQa = (const float*)d_in[3];
    const float* WKa = (const float*)d_in[4];
    const float* WVa = (const float*)d_in[5];
    const float* bVa = (const float*)d_in[6];
    const float* WQe = (const float*)d_in[7];
    const float* WKe = (const float*)d_in[8];
    const float* WVe = (const float*)d_in[9];
    const float* bVe = (const float*)d_in[10];
    float* out = (float*)d_out;

    char* ws = (char*)d_ws;
    float* featT = (float*)(ws);                    // 33.5 MB: [N][128]
    float* qeff  = (float*)(ws + 33554432);         // 33.5 MB: [N][128]
    float* Mmat  = (float*)(ws + 67108864);         // 32 KB: [2][64][64]
    float* sT    = qeff;                            // alias: read-then-write per point

    k_pack<<<1024, 256, 0, stream>>>(spa, spe, featT);
    k_matM<<<1, 256, 0, stream>>>(WQa, WKa, WQe, WKe, Mmat);
    k_qeff<<<1024, 256, 0, stream>>>(featT, Mmat, qeff);
    k_attn<<<16384, 256, 0, stream>>>(featT, qeff, idx, sT);
    k_out<<<1024, 256, 0, stream>>>(sT, spa, spe, WVa, bVa, WVe, bVe, out);
}

// Round 3
// 252.895 us; speedup vs baseline: 1.2910x; 1.2910x over previous
//
#include <hip/hip_runtime.h>

#define NPTS 65536

__device__ __forceinline__ float dot4(float4 a, float4 b) {
    return a.x * b.x + a.y * b.y + a.z * b.z + a.w * b.w;
}

// ---------------- Kernel 1: M = WQ^T * WK for both attentions ----------------
__global__ __launch_bounds__(256) void k_matM(const float* __restrict__ WQa,
                                              const float* __restrict__ WKa,
                                              const float* __restrict__ WQe,
                                              const float* __restrict__ WKe,
                                              float* __restrict__ M) {
    const int t = threadIdx.x;
    for (int i = 0; i < 32; ++i) {
        const int id = t + (i << 8);      // 0..8191
        const int which = id >> 12;       // 0: spa, 1: spe
        const int c = (id >> 6) & 63;
        const int e = id & 63;
        const float* WQ = which ? WQe : WQa;
        const float* WK = which ? WKe : WKa;
        float acc = 0.f;
        #pragma unroll
        for (int d = 0; d < 64; ++d) acc += WQ[d * 64 + c] * WK[d * 64 + e];
        M[id] = acc;                      // M[which][c][e]
    }
}

// ------- Kernel 2: fused pack (featT[N][128]) + qeff[n][e']=sum_c q[c]M[c][e']
__global__ __launch_bounds__(256) void k_prep(const float* __restrict__ spa,
                                              const float* __restrict__ spe,
                                              const float* __restrict__ M,
                                              float* __restrict__ featT,
                                              float* __restrict__ qeff) {
    __shared__ float tile[64][132];   // 528B rows, float4-aligned
    const int n0 = blockIdx.x * 64;
    const int t = threadIdx.x;
    {
        const int p = t & 63;         // lanes contiguous over points -> coalesced
        const int c0 = t >> 6;
        #pragma unroll
        for (int i = 0; i < 32; ++i) {
            const int c = c0 + (i << 2);
            tile[p][c] = (c < 64) ? spa[c * NPTS + n0 + p]
                                  : spe[(c - 64) * NPTS + n0 + p];
        }
    }
    __syncthreads();
    const int c = t & 127;
    const int p0 = t >> 7;
    #pragma unroll
    for (int i = 0; i < 32; ++i) {    // transpose-write featT (coalesced rows)
        const int p = p0 + (i << 1);
        featT[(size_t)(n0 + p) * 128 + c] = tile[p][c];
    }
    // qeff: output channel c; spa half feeds qeff[0..64), spe half feeds [64..128)
    const int which = c >> 6;
    const int e = c & 63;
    float mcol[64];
    #pragma unroll
    for (int cc = 0; cc < 64; ++cc) mcol[cc] = M[which * 4096 + cc * 64 + e];
    for (int i = 0; i < 32; ++i) {
        const int p = p0 + (i << 1);
        const float4* fr = reinterpret_cast<const float4*>(&tile[p][which << 6]);
        float acc = 0.f;
        #pragma unroll
        for (int c4 = 0; c4 < 16; ++c4) {
            const float4 v = fr[c4];
            acc += v.x * mcol[4*c4] + v.y * mcol[4*c4+1] + v.z * mcol[4*c4+2] + v.w * mcol[4*c4+3];
        }
        qeff[(size_t)(n0 + p) * 128 + c] = acc;
    }
}

// ---------------- Kernel 3: attention (1 wave = 1 point, lane = k*4+c4) ------
// NOTE: qeff and sT ALIAS (same buffer) -> no __restrict__ on either.
__global__ __launch_bounds__(256) void k_attn(const float* __restrict__ featT,
                                              const float* qeff,
                                              const int* __restrict__ idx,
                                              float* sT) {
    // per-wave reduce tile; stride 76 words: 12k mod 32 spreads writes over
    // all 8 bank-quads (b128), reads (12k+c)%32 are 2-way -> free
    __shared__ float red[4][16][76];
    const int wave = threadIdx.x >> 6;
    const int lane = threadIdx.x & 63;
    const int n = blockIdx.x * 4 + wave;
    const int k = lane >> 2;          // neighbor owned by this lane
    const int c4 = lane & 3;          // channel quarter (16 channels)

    const int j = idx[n * 16 + k];    // 4 lanes same addr -> broadcast
    const float4* fx = reinterpret_cast<const float4*>(featT + (size_t)j * 128 + c4 * 16);
    const float4 xa0 = fx[0],  xa1 = fx[1],  xa2 = fx[2],  xa3 = fx[3];   // spa half
    const float4 xe0 = fx[16], xe1 = fx[17], xe2 = fx[18], xe3 = fx[19];  // spe half
    const float4* qx = reinterpret_cast<const float4*>(qeff + (size_t)n * 128 + c4 * 16);
    const float4 qa0 = qx[0],  qa1 = qx[1],  qa2 = qx[2],  qa3 = qx[3];
    const float4 qe0 = qx[16], qe1 = qx[17], qe2 = qx[18], qe3 = qx[19];

    // scores: spa att = q_spa . x_spe ; spe att = q_spe . x_spa
    float pa = dot4(qa0, xe0) + dot4(qa1, xe1) + dot4(qa2, xe2) + dot4(qa3, xe3);
    float pe = dot4(qe0, xa0) + dot4(qe1, xa1) + dot4(qe2, xa2) + dot4(qe3, xa3);
    pa += __shfl_xor(pa, 1); pa += __shfl_xor(pa, 2);   // reduce over c4
    pe += __shfl_xor(pe, 1); pe += __shfl_xor(pe, 2);
    const float sa = pa * 0.125f;     // / sqrt(64)
    const float se = pe * 0.125f;

    // softmax over k: xor{4,8,16,32} visits the 16 lanes sharing c4 — each of
    // the 16 distinct k exactly ONCE (bits 2..5 are the k bits).
    float ma = sa, me = se;
    #pragma unroll
    for (int m = 4; m < 64; m <<= 1) {
        ma = fmaxf(ma, __shfl_xor(ma, m));
        me = fmaxf(me, __shfl_xor(me, m));
    }
    const float ea = __expf(sa - ma);
    const float ee = __expf(se - me);
    float da = ea, de = ee;
    #pragma unroll
    for (int m = 4; m < 64; m <<= 1) {
        da += __shfl_xor(da, m);
        de += __shfl_xor(de, m);
    }
    const float wA = ea / da;         // da = sum over the 16 k, counted once each
    const float wB = ee / de;

    float4* row4 = reinterpret_cast<float4*>(&red[wave][k][c4 * 16]);
    // ---- pass 1: ctx_spa from spe half ----
    row4[0] = make_float4(wA*xe0.x, wA*xe0.y, wA*xe0.z, wA*xe0.w);
    row4[1] = make_float4(wA*xe1.x, wA*xe1.y, wA*xe1.z, wA*xe1.w);
    row4[2] = make_float4(wA*xe2.x, wA*xe2.y, wA*xe2.z, wA*xe2.w);
    row4[3] = make_float4(wA*xe3.x, wA*xe3.y, wA*xe3.z, wA*xe3.w);
    asm volatile("s_waitcnt lgkmcnt(0)" ::: "memory");  // wave-internal fence
    float sumA = 0.f;
    #pragma unroll
    for (int kk = 0; kk < 16; ++kk) sumA += red[wave][kk][lane];
    sT[(size_t)n * 128 + lane] = sumA;
    asm volatile("s_waitcnt lgkmcnt(0)" ::: "memory");  // reads done before overwrite
    // ---- pass 2: ctx_spe from spa half ----
    row4[0] = make_float4(wB*xa0.x, wB*xa0.y, wB*xa0.z, wB*xa0.w);
    row4[1] = make_float4(wB*xa1.x, wB*xa1.y, wB*xa1.z, wB*xa1.w);
    row4[2] = make_float4(wB*xa2.x, wB*xa2.y, wB*xa2.z, wB*xa2.w);
    row4[3] = make_float4(wB*xa3.x, wB*xa3.y, wB*xa3.z, wB*xa3.w);
    asm volatile("s_waitcnt lgkmcnt(0)" ::: "memory");
    float sumE = 0.f;
    #pragma unroll
    for (int kk = 0; kk < 16; ++kk) sumE += red[wave][kk][lane];
    sT[(size_t)n * 128 + 64 + lane] = sumE;
}

// ---------------- Kernel 4: ctx = WV*s + b, residual, transpose-write --------
__global__ __launch_bounds__(256) void k_out(const float* __restrict__ sT,
                                             const float* __restrict__ spa,
                                             const float* __restrict__ spe,
                                             const float* __restrict__ WVa,
                                             const float* __restrict__ bVa,
                                             const float* __restrict__ WVe,
                                             const float* __restrict__ bVe,
                                             float* __restrict__ out) {
    __shared__ float stile[64][132];
    __shared__ float wv[2][64][65];
    const int n0 = blockIdx.x * 64;
    const int t = threadIdx.x;
    {
        const int c = t & 127;
        const int p0 = t >> 7;
        #pragma unroll
        for (int i = 0; i < 32; ++i) {
            const int p = p0 + (i << 1);
            stile[p][c] = sT[(size_t)(n0 + p) * 128 + c];
        }
    }
    {
        #pragma unroll
        for (int i = 0; i < 32; ++i) {
            const int id = t + (i << 8);
            const int w = id >> 12;
            const int dd = (id >> 6) & 63;
            const int e = id & 63;
            wv[w][dd][e] = (w ? WVe : WVa)[dd * 64 + e];
        }
    }
    __syncthreads();
    const int d = t & 127;            // output channel
    const int which = d >> 6;
    const int dd = d & 63;
    float wrow[64];
    #pragma unroll
    for (int e = 0; e < 64; ++e) wrow[e] = wv[which][dd][e];
    const float bias = which ? bVe[dd] : bVa[dd];
    const int p0 = t >> 7;
    float acc[32];
    #pragma unroll
    for (int i = 0; i < 32; ++i) {
        const int p = p0 + (i << 1);
        const float4* sr = reinterpret_cast<const float4*>(&stile[p][which << 6]);
        float a = bias;
        #pragma unroll
        for (int e4 = 0; e4 < 16; ++e4) {
            const float4 v = sr[e4];
            a += v.x * wrow[4*e4] + v.y * wrow[4*e4+1] + v.z * wrow[4*e4+2] + v.w * wrow[4*e4+3];
        }
        acc[i] = a;
    }
    __syncthreads();
    #pragma unroll
    for (int i = 0; i < 32; ++i) {
        const int p = p0 + (i << 1);
        stile[p][d] = acc[i];         // reuse stile as ctx tile
    }
    __syncthreads();
    {
        const int p = t & 63;
        const int d0 = t >> 6;
        #pragma unroll
        for (int i = 0; i < 32; ++i) {
            const int ch = d0 + (i << 2);
            const float f = (ch < 64) ? spa[ch * NPTS + n0 + p]
                                      : spe[(ch - 64) * NPTS + n0 + p];
            out[(size_t)ch * NPTS + n0 + p] = f + stile[p][ch];
        }
    }
}

extern "C" void kernel_launch(void* const* d_in, const int* in_sizes, int n_in,
                              void* d_out, int out_size, void* d_ws, size_t ws_size,
                              hipStream_t stream) {
    const float* spa = (const float*)d_in[0];
    const float* spe = (const float*)d_in[1];
    const int* idx   = (const int*)d_in[2];
    const float* WQa = (const float*)d_in[3];
    const float* WKa = (const float*)d_in[4];
    const float* WVa = (const float*)d_in[5];
    const float* bVa = (const float*)d_in[6];
    const float* WQe = (const float*)d_in[7];
    const float* WKe = (const float*)d_in[8];
    const float* WVe = (const float*)d_in[9];
    const float* bVe = (const float*)d_in[10];
    float* out = (float*)d_out;

    char* ws = (char*)d_ws;
    float* featT = (float*)(ws);                    // 33.5 MB: [N][128]
    float* qeff  = (float*)(ws + 33554432);         // 33.5 MB: [N][128]
    float* Mmat  = (float*)(ws + 67108864);         // 32 KB: [2][64][64]
    float* sT    = qeff;                            // alias: each wave reads its own
                                                    // qeff row before writing sT row

    k_matM<<<1, 256, 0, stream>>>(WQa, WKa, WQe, WKe, Mmat);
    k_prep<<<1024, 256, 0, stream>>>(spa, spe, Mmat, featT, qeff);
    k_attn<<<16384, 256, 0, stream>>>(featT, qeff, idx, sT);
    k_out<<<1024, 256, 0, stream>>>(sT, spa, spe, WVa, bVa, WVe, bVe, out);
}

// Round 4
// 158.558 us; speedup vs baseline: 2.0592x; 1.5950x over previous
//
#include <hip/hip_runtime.h>

#define NPTS 65536

__device__ __forceinline__ float dot4(float4 a, float4 b) {
    return a.x * b.x + a.y * b.y + a.z * b.z + a.w * b.w;
}

// ---------------- Kernel 1: M = WQ^T * WK for both attentions ----------------
// 8 blocks: which = b>>2, c-slice = (b&3)*16. LDS-staged, float4 outputs.
__global__ __launch_bounds__(256) void k_matM(const float* __restrict__ WQa,
                                              const float* __restrict__ WKa,
                                              const float* __restrict__ WQe,
                                              const float* __restrict__ WKe,
                                              float* __restrict__ M) {
    __shared__ float WKs[4096];       // full WK, row-major [d][e], stride 64
    __shared__ float WQs[64][16];     // WQ columns c0..c0+15: WQs[d][cc]
    const int which = blockIdx.x >> 2;
    const int c0 = (blockIdx.x & 3) * 16;
    const float* WQ = which ? (const float*)WQe : (const float*)WQa;
    const float* WK = which ? (const float*)WKe : (const float*)WKa;
    const int t = threadIdx.x;
    #pragma unroll
    for (int i = 0; i < 16; ++i) WKs[t + i * 256] = WK[t + i * 256];
    #pragma unroll
    for (int i = 0; i < 4; ++i) {
        const int id = t + i * 256;   // 0..1023
        const int d = id >> 4;
        const int cc = id & 15;
        WQs[d][cc] = WQ[d * 64 + c0 + cc];
    }
    __syncthreads();
    const int cc = t >> 4;            // 0..15
    const int eg = t & 15;            // e = eg*4
    float4 acc = make_float4(0.f, 0.f, 0.f, 0.f);
    #pragma unroll
    for (int d = 0; d < 64; ++d) {
        const float wq = WQs[d][cc];
        const float4 wk = *reinterpret_cast<const float4*>(&WKs[d * 64 + eg * 4]);
        acc.x += wq * wk.x; acc.y += wq * wk.y;
        acc.z += wq * wk.z; acc.w += wq * wk.w;
    }
    *reinterpret_cast<float4*>(&M[which * 4096 + (c0 + cc) * 64 + eg * 4]) = acc;
}

// ------- Kernel 2: fused pack (featT[N][128]) + qeff[n][e']=sum_c q[c]M[c][e']
__global__ __launch_bounds__(256) void k_prep(const float* __restrict__ spa,
                                              const float* __restrict__ spe,
                                              const float* __restrict__ M,
                                              float* __restrict__ featT,
                                              float* __restrict__ qeff) {
    __shared__ float tile[64][132];   // 528B rows, float4-aligned
    const int n0 = blockIdx.x * 64;
    const int t = threadIdx.x;
    {
        const int p = t & 63;         // lanes contiguous over points -> coalesced
        const int c0 = t >> 6;
        #pragma unroll
        for (int i = 0; i < 32; ++i) {
            const int c = c0 + (i << 2);
            tile[p][c] = (c < 64) ? spa[c * NPTS + n0 + p]
                                  : spe[(c - 64) * NPTS + n0 + p];
        }
    }
    __syncthreads();
    const int c = t & 127;
    const int p0 = t >> 7;
    #pragma unroll
    for (int i = 0; i < 32; ++i) {    // transpose-write featT (coalesced rows)
        const int p = p0 + (i << 1);
        featT[(size_t)(n0 + p) * 128 + c] = tile[p][c];
    }
    // qeff: output channel c; spa half feeds qeff[0..64), spe half feeds [64..128)
    const int which = c >> 6;
    const int e = c & 63;
    float mcol[64];
    #pragma unroll
    for (int cc = 0; cc < 64; ++cc) mcol[cc] = M[which * 4096 + cc * 64 + e];
    for (int i = 0; i < 32; ++i) {
        const int p = p0 + (i << 1);
        const float4* fr = reinterpret_cast<const float4*>(&tile[p][which << 6]);
        float acc = 0.f;
        #pragma unroll
        for (int c4 = 0; c4 < 16; ++c4) {
            const float4 v = fr[c4];
            acc += v.x * mcol[4*c4] + v.y * mcol[4*c4+1] + v.z * mcol[4*c4+2] + v.w * mcol[4*c4+3];
        }
        qeff[(size_t)(n0 + p) * 128 + c] = acc;
    }
}

// ---------------- Kernel 3: attention (1 wave = 1 point, lane = k*4+c4) ------
// NOTE: qeff and sT ALIAS (same buffer) -> no __restrict__ on either.
__global__ __launch_bounds__(256) void k_attn(const float* __restrict__ featT,
                                              const float* qeff,
                                              const int* __restrict__ idx,
                                              float* sT) {
    // per-wave reduce tile; stride 76 words: 12k mod 32 spreads writes over
    // all 8 bank-quads (b128), reads (12k+c)%32 are 2-way -> free
    __shared__ float red[4][16][76];
    const int wave = threadIdx.x >> 6;
    const int lane = threadIdx.x & 63;
    const int n = blockIdx.x * 4 + wave;
    const int k = lane >> 2;          // neighbor owned by this lane
    const int c4 = lane & 3;          // channel quarter (16 channels)

    const int j = idx[n * 16 + k];    // 4 lanes same addr -> broadcast
    const float4* fx = reinterpret_cast<const float4*>(featT + (size_t)j * 128 + c4 * 16);
    const float4 xa0 = fx[0],  xa1 = fx[1],  xa2 = fx[2],  xa3 = fx[3];   // spa half
    const float4 xe0 = fx[16], xe1 = fx[17], xe2 = fx[18], xe3 = fx[19];  // spe half
    const float4* qx = reinterpret_cast<const float4*>(qeff + (size_t)n * 128 + c4 * 16);
    const float4 qa0 = qx[0],  qa1 = qx[1],  qa2 = qx[2],  qa3 = qx[3];
    const float4 qe0 = qx[16], qe1 = qx[17], qe2 = qx[18], qe3 = qx[19];

    // scores: spa att = q_spa . x_spe ; spe att = q_spe . x_spa
    float pa = dot4(qa0, xe0) + dot4(qa1, xe1) + dot4(qa2, xe2) + dot4(qa3, xe3);
    float pe = dot4(qe0, xa0) + dot4(qe1, xa1) + dot4(qe2, xa2) + dot4(qe3, xa3);
    pa += __shfl_xor(pa, 1); pa += __shfl_xor(pa, 2);   // reduce over c4
    pe += __shfl_xor(pe, 1); pe += __shfl_xor(pe, 2);
    const float sa = pa * 0.125f;     // / sqrt(64)
    const float se = pe * 0.125f;

    // softmax over k: xor{4,8,16,32} visits the 16 lanes sharing c4 — each of
    // the 16 distinct k exactly ONCE (bits 2..5 are the k bits).
    float ma = sa, me = se;
    #pragma unroll
    for (int m = 4; m < 64; m <<= 1) {
        ma = fmaxf(ma, __shfl_xor(ma, m));
        me = fmaxf(me, __shfl_xor(me, m));
    }
    const float ea = __expf(sa - ma);
    const float ee = __expf(se - me);
    float da = ea, de = ee;
    #pragma unroll
    for (int m = 4; m < 64; m <<= 1) {
        da += __shfl_xor(da, m);
        de += __shfl_xor(de, m);
    }
    const float wA = ea / da;         // da = sum over the 16 k, counted once each
    const float wB = ee / de;

    float4* row4 = reinterpret_cast<float4*>(&red[wave][k][c4 * 16]);
    // ---- pass 1: ctx_spa from spe half ----
    row4[0] = make_float4(wA*xe0.x, wA*xe0.y, wA*xe0.z, wA*xe0.w);
    row4[1] = make_float4(wA*xe1.x, wA*xe1.y, wA*xe1.z, wA*xe1.w);
    row4[2] = make_float4(wA*xe2.x, wA*xe2.y, wA*xe2.z, wA*xe2.w);
    row4[3] = make_float4(wA*xe3.x, wA*xe3.y, wA*xe3.z, wA*xe3.w);
    asm volatile("s_waitcnt lgkmcnt(0)" ::: "memory");  // wave-internal fence
    float sumA = 0.f;
    #pragma unroll
    for (int kk = 0; kk < 16; ++kk) sumA += red[wave][kk][lane];
    sT[(size_t)n * 128 + lane] = sumA;
    asm volatile("s_waitcnt lgkmcnt(0)" ::: "memory");  // reads done before overwrite
    // ---- pass 2: ctx_spe from spa half ----
    row4[0] = make_float4(wB*xa0.x, wB*xa0.y, wB*xa0.z, wB*xa0.w);
    row4[1] = make_float4(wB*xa1.x, wB*xa1.y, wB*xa1.z, wB*xa1.w);
    row4[2] = make_float4(wB*xa2.x, wB*xa2.y, wB*xa2.z, wB*xa2.w);
    row4[3] = make_float4(wB*xa3.x, wB*xa3.y, wB*xa3.z, wB*xa3.w);
    asm volatile("s_waitcnt lgkmcnt(0)" ::: "memory");
    float sumE = 0.f;
    #pragma unroll
    for (int kk = 0; kk < 16; ++kk) sumE += red[wave][kk][lane];
    sT[(size_t)n * 128 + 64 + lane] = sumE;
}

// ---------------- Kernel 4: ctx = WV*s + b, residual, transpose-write --------
__global__ __launch_bounds__(256) void k_out(const float* __restrict__ sT,
                                             const float* __restrict__ spa,
                                             const float* __restrict__ spe,
                                             const float* __restrict__ WVa,
                                             const float* __restrict__ bVa,
                                             const float* __restrict__ WVe,
                                             const float* __restrict__ bVe,
                                             float* __restrict__ out) {
    __shared__ float stile[64][132];
    __shared__ float wv[2][64][65];
    const int n0 = blockIdx.x * 64;
    const int t = threadIdx.x;
    {
        const int c = t & 127;
        const int p0 = t >> 7;
        #pragma unroll
        for (int i = 0; i < 32; ++i) {
            const int p = p0 + (i << 1);
            stile[p][c] = sT[(size_t)(n0 + p) * 128 + c];
        }
    }
    {
        #pragma unroll
        for (int i = 0; i < 32; ++i) {
            const int id = t + (i << 8);
            const int w = id >> 12;
            const int dd = (id >> 6) & 63;
            const int e = id & 63;
            wv[w][dd][e] = (w ? WVe : WVa)[dd * 64 + e];
        }
    }
    __syncthreads();
    const int d = t & 127;            // output channel
    const int which = d >> 6;
    const int dd = d & 63;
    float wrow[64];
    #pragma unroll
    for (int e = 0; e < 64; ++e) wrow[e] = wv[which][dd][e];
    const float bias = which ? bVe[dd] : bVa[dd];
    const int p0 = t >> 7;
    float acc[32];
    #pragma unroll
    for (int i = 0; i < 32; ++i) {
        const int p = p0 + (i << 1);
        const float4* sr = reinterpret_cast<const float4*>(&stile[p][which << 6]);
        float a = bias;
        #pragma unroll
        for (int e4 = 0; e4 < 16; ++e4) {
            const float4 v = sr[e4];
            a += v.x * wrow[4*e4] + v.y * wrow[4*e4+1] + v.z * wrow[4*e4+2] + v.w * wrow[4*e4+3];
        }
        acc[i] = a;
    }
    __syncthreads();
    #pragma unroll
    for (int i = 0; i < 32; ++i) {
        const int p = p0 + (i << 1);
        stile[p][d] = acc[i];         // reuse stile as ctx tile
    }
    __syncthreads();
    {
        const int p = t & 63;
        const int d0 = t >> 6;
        #pragma unroll
        for (int i = 0; i < 32; ++i) {
            const int ch = d0 + (i << 2);
            const float f = (ch < 64) ? spa[ch * NPTS + n0 + p]
                                      : spe[(ch - 64) * NPTS + n0 + p];
            out[(size_t)ch * NPTS + n0 + p] = f + stile[p][ch];
        }
    }
}

extern "C" void kernel_launch(void* const* d_in, const int* in_sizes, int n_in,
                              void* d_out, int out_size, void* d_ws, size_t ws_size,
                              hipStream_t stream) {
    const float* spa = (const float*)d_in[0];
    const float* spe = (const float*)d_in[1];
    const int* idx   = (const int*)d_in[2];
    const float* WQa = (const float*)d_in[3];
    const float* WKa = (const float*)d_in[4];
    const float* WVa = (const float*)d_in[5];
    const float* bVa = (const float*)d_in[6];
    const float* WQe = (const float*)d_in[7];
    const float* WKe = (const float*)d_in[8];
    const float* WVe = (const float*)d_in[9];
    const float* bVe = (const float*)d_in[10];
    float* out = (float*)d_out;

    char* ws = (char*)d_ws;
    float* featT = (float*)(ws);                    // 33.5 MB: [N][128]
    float* qeff  = (float*)(ws + 33554432);         // 33.5 MB: [N][128]
    float* Mmat  = (float*)(ws + 67108864);         // 32 KB: [2][64][64]
    float* sT    = qeff;                            // alias: each wave reads its own
                                                    // qeff row before writing sT row

    k_matM<<<8, 256, 0, stream>>>(WQa, WKa, WQe, WKe, Mmat);
    k_prep<<<1024, 256, 0, stream>>>(spa, spe, Mmat, featT, qeff);
    k_attn<<<16384, 256, 0, stream>>>(featT, qeff, idx, sT);
    k_out<<<1024, 256, 0, stream>>>(sT, spa, spe, WVa, bVa, WVe, bVe, out);
}

// Round 5
// 125.209 us; speedup vs baseline: 2.6076x; 1.2664x over previous
//
#include <hip/hip_runtime.h>

#define NPTS 65536

__device__ __forceinline__ float bf_lo(unsigned u) { return __uint_as_float(u << 16); }
__device__ __forceinline__ float bf_hi(unsigned u) { return __uint_as_float(u & 0xFFFF0000u); }
__device__ __forceinline__ unsigned short f2bf(float f) {      // RNE round
    unsigned u = __float_as_uint(f);
    return (unsigned short)((u + 0x7FFFu + ((u >> 16) & 1u)) >> 16);
}
__device__ __forceinline__ void unpack8(uint4 v, float* o) {
    o[0] = bf_lo(v.x); o[1] = bf_hi(v.x); o[2] = bf_lo(v.y); o[3] = bf_hi(v.y);
    o[4] = bf_lo(v.z); o[5] = bf_hi(v.z); o[6] = bf_lo(v.w); o[7] = bf_hi(v.w);
}
__device__ __forceinline__ float dot8q(uint4 q, const float* x) {
    float s;
    s  = bf_lo(q.x) * x[0] + bf_hi(q.x) * x[1];
    s += bf_lo(q.y) * x[2] + bf_hi(q.y) * x[3];
    s += bf_lo(q.z) * x[4] + bf_hi(q.z) * x[5];
    s += bf_lo(q.w) * x[6] + bf_hi(q.w) * x[7];
    return s;
}

// ---------------- Kernel 1: M = WQ^T * WK for both attentions ----------------
__global__ __launch_bounds__(256) void k_matM(const float* __restrict__ WQa,
                                              const float* __restrict__ WKa,
                                              const float* __restrict__ WQe,
                                              const float* __restrict__ WKe,
                                              float* __restrict__ M) {
    __shared__ float WKs[4096];       // full WK, row-major [d][e], stride 64
    __shared__ float WQs[64][16];     // WQ columns c0..c0+15: WQs[d][cc]
    const int which = blockIdx.x >> 2;
    const int c0 = (blockIdx.x & 3) * 16;
    const float* WQ = which ? WQe : WQa;
    const float* WK = which ? WKe : WKa;
    const int t = threadIdx.x;
    #pragma unroll
    for (int i = 0; i < 16; ++i) WKs[t + i * 256] = WK[t + i * 256];
    #pragma unroll
    for (int i = 0; i < 4; ++i) {
        const int id = t + i * 256;
        WQs[id >> 4][id & 15] = WQ[(id >> 4) * 64 + c0 + (id & 15)];
    }
    __syncthreads();
    const int cc = t >> 4;
    const int eg = t & 15;
    float4 acc = make_float4(0.f, 0.f, 0.f, 0.f);
    #pragma unroll
    for (int d = 0; d < 64; ++d) {
        const float wq = WQs[d][cc];
        const float4 wk = *reinterpret_cast<const float4*>(&WKs[d * 64 + eg * 4]);
        acc.x += wq * wk.x; acc.y += wq * wk.y;
        acc.z += wq * wk.z; acc.w += wq * wk.w;
    }
    *reinterpret_cast<float4*>(&M[which * 4096 + (c0 + cc) * 64 + eg * 4]) = acc;
}

// ------- Kernel 2: fused pack (featT bf16) + qeff (bf16) ---------------------
__global__ __launch_bounds__(256) void k_prep(const float* __restrict__ spa,
                                              const float* __restrict__ spe,
                                              const float* __restrict__ M,
                                              unsigned short* __restrict__ featT,
                                              unsigned short* __restrict__ qeff) {
    __shared__ float tile[64][132];   // f32 staging, float4-aligned rows
    const int n0 = blockIdx.x * 64;
    const int t = threadIdx.x;
    {
        const int p = t & 63;
        const int c0 = t >> 6;
        #pragma unroll
        for (int i = 0; i < 32; ++i) {
            const int c = c0 + (i << 2);
            tile[p][c] = (c < 64) ? spa[c * NPTS + n0 + p]
                                  : spe[(c - 64) * NPTS + n0 + p];
        }
    }
    __syncthreads();
    const int c = t & 127;
    const int p0 = t >> 7;
    #pragma unroll
    for (int i = 0; i < 32; ++i) {    // bf16 pack-write (coalesced 128B/wave)
        const int p = p0 + (i << 1);
        featT[(size_t)(n0 + p) * 128 + c] = f2bf(tile[p][c]);
    }
    const int which = c >> 6;
    const int e = c & 63;
    float mcol[64];
    #pragma unroll
    for (int cc = 0; cc < 64; ++cc) mcol[cc] = M[which * 4096 + cc * 64 + e];
    for (int i = 0; i < 32; ++i) {
        const int p = p0 + (i << 1);
        const float4* fr = reinterpret_cast<const float4*>(&tile[p][which << 6]);
        float a0 = 0.f, a1 = 0.f, a2 = 0.f, a3 = 0.f;   // ILP-4 accumulators
        #pragma unroll
        for (int c4 = 0; c4 < 16; c4 += 4) {
            const float4 v0 = fr[c4],     v1 = fr[c4 + 1];
            const float4 v2 = fr[c4 + 2], v3 = fr[c4 + 3];
            a0 += v0.x*mcol[4*c4]    + v0.y*mcol[4*c4+1]  + v0.z*mcol[4*c4+2]  + v0.w*mcol[4*c4+3];
            a1 += v1.x*mcol[4*c4+4]  + v1.y*mcol[4*c4+5]  + v1.z*mcol[4*c4+6]  + v1.w*mcol[4*c4+7];
            a2 += v2.x*mcol[4*c4+8]  + v2.y*mcol[4*c4+9]  + v2.z*mcol[4*c4+10] + v2.w*mcol[4*c4+11];
            a3 += v3.x*mcol[4*c4+12] + v3.y*mcol[4*c4+13] + v3.z*mcol[4*c4+14] + v3.w*mcol[4*c4+15];
        }
        qeff[(size_t)(n0 + p) * 128 + c] = f2bf((a0 + a1) + (a2 + a3));
    }
}

// ---------------- Kernel 3: attention (1 wave = 1 point, lane = k*4+c4) ------
__global__ __launch_bounds__(256) void k_attn(const unsigned short* __restrict__ featT,
                                              const unsigned short* __restrict__ qeff,
                                              const int* __restrict__ idx,
                                              float* __restrict__ sT) {
    __shared__ float red[4][16][76];
    const int wave = threadIdx.x >> 6;
    const int lane = threadIdx.x & 63;
    const int n = blockIdx.x * 4 + wave;
    const int k = lane >> 2;          // neighbor owned by this lane
    const int c4 = lane & 3;          // channel quarter (16 channels)

    const int j = idx[n * 16 + k];    // 4 lanes same addr -> broadcast
    // bf16 row = 256B = 16 uint4; lane's quarter: uint4s 2*c4, 2*c4+1 (+8 for spe)
    const uint4* fx = reinterpret_cast<const uint4*>(featT + (size_t)j * 128);
    const uint4 A0 = fx[2*c4], A1 = fx[2*c4 + 1];        // spa 16 ch
    const uint4 E0 = fx[8 + 2*c4], E1 = fx[8 + 2*c4 + 1];// spe 16 ch
    const uint4* qx = reinterpret_cast<const uint4*>(qeff + (size_t)n * 128);
    const uint4 QA0 = qx[2*c4], QA1 = qx[2*c4 + 1];
    const uint4 QE0 = qx[8 + 2*c4], QE1 = qx[8 + 2*c4 + 1];

    float xa[16], xe[16];
    unpack8(A0, xa); unpack8(A1, xa + 8);
    unpack8(E0, xe); unpack8(E1, xe + 8);

    // scores: spa att = q_spa . x_spe ; spe att = q_spe . x_spa
    float pa = dot8q(QA0, xe) + dot8q(QA1, xe + 8);
    float pe = dot8q(QE0, xa) + dot8q(QE1, xa + 8);
    pa += __shfl_xor(pa, 1); pa += __shfl_xor(pa, 2);   // reduce over c4
    pe += __shfl_xor(pe, 1); pe += __shfl_xor(pe, 2);
    const float sa = pa * 0.125f;     // / sqrt(64)
    const float se = pe * 0.125f;

    // softmax over k: xor{4,8,16,32} visits each of the 16 k exactly once
    float ma = sa, me = se;
    #pragma unroll
    for (int m = 4; m < 64; m <<= 1) {
        ma = fmaxf(ma, __shfl_xor(ma, m));
        me = fmaxf(me, __shfl_xor(me, m));
    }
    const float ea = __expf(sa - ma);
    const float ee = __expf(se - me);
    float da = ea, de = ee;
    #pragma unroll
    for (int m = 4; m < 64; m <<= 1) {
        da += __shfl_xor(da, m);
        de += __shfl_xor(de, m);
    }
    const float wA = ea / da;
    const float wB = ee / de;

    float4* row4 = reinterpret_cast<float4*>(&red[wave][k][c4 * 16]);
    // ---- pass 1: ctx_spa from spe half ----
    row4[0] = make_float4(wA*xe[0],  wA*xe[1],  wA*xe[2],  wA*xe[3]);
    row4[1] = make_float4(wA*xe[4],  wA*xe[5],  wA*xe[6],  wA*xe[7]);
    row4[2] = make_float4(wA*xe[8],  wA*xe[9],  wA*xe[10], wA*xe[11]);
    row4[3] = make_float4(wA*xe[12], wA*xe[13], wA*xe[14], wA*xe[15]);
    asm volatile("s_waitcnt lgkmcnt(0)" ::: "memory");  // wave-internal fence
    float sumA = 0.f;
    #pragma unroll
    for (int kk = 0; kk < 16; ++kk) sumA += red[wave][kk][lane];
    sT[(size_t)n * 128 + lane] = sumA;
    asm volatile("s_waitcnt lgkmcnt(0)" ::: "memory");  // reads done before overwrite
    // ---- pass 2: ctx_spe from spa half ----
    row4[0] = make_float4(wB*xa[0],  wB*xa[1],  wB*xa[2],  wB*xa[3]);
    row4[1] = make_float4(wB*xa[4],  wB*xa[5],  wB*xa[6],  wB*xa[7]);
    row4[2] = make_float4(wB*xa[8],  wB*xa[9],  wB*xa[10], wB*xa[11]);
    row4[3] = make_float4(wB*xa[12], wB*xa[13], wB*xa[14], wB*xa[15]);
    asm volatile("s_waitcnt lgkmcnt(0)" ::: "memory");
    float sumE = 0.f;
    #pragma unroll
    for (int kk = 0; kk < 16; ++kk) sumE += red[wave][kk][lane];
    sT[(size_t)n * 128 + 64 + lane] = sumE;
}

// ---------------- Kernel 4: ctx = WV*s + b, residual, transpose-write --------
__global__ __launch_bounds__(256) void k_out(const float* __restrict__ sT,
                                             const float* __restrict__ spa,
                                             const float* __restrict__ spe,
                                             const float* __restrict__ WVa,
                                             const float* __restrict__ bVa,
                                             const float* __restrict__ WVe,
                                             const float* __restrict__ bVe,
                                             float* __restrict__ out) {
    __shared__ float stile[64][132];
    __shared__ float wv[2][64][65];
    const int n0 = blockIdx.x * 64;
    const int t = threadIdx.x;
    {
        const int c = t & 127;
        const int p0 = t >> 7;
        #pragma unroll
        for (int i = 0; i < 32; ++i) {
            const int p = p0 + (i << 1);
            stile[p][c] = sT[(size_t)(n0 + p) * 128 + c];
        }
    }
    {
        #pragma unroll
        for (int i = 0; i < 32; ++i) {
            const int id = t + (i << 8);
            const int w = id >> 12;
            const int dd = (id >> 6) & 63;
            const int e = id & 63;
            wv[w][dd][e] = (w ? WVe : WVa)[dd * 64 + e];
        }
    }
    __syncthreads();
    const int d = t & 127;
    const int which = d >> 6;
    const int dd = d & 63;
    float wrow[64];
    #pragma unroll
    for (int e = 0; e < 64; ++e) wrow[e] = wv[which][dd][e];
    const float bias = which ? bVe[dd] : bVa[dd];
    const int p0 = t >> 7;
    float acc[32];
    #pragma unroll
    for (int i = 0; i < 32; ++i) {
        const int p = p0 + (i << 1);
        const float4* sr = reinterpret_cast<const float4*>(&stile[p][which << 6]);
        float a = bias;
        #pragma unroll
        for (int e4 = 0; e4 < 16; ++e4) {
            const float4 v = sr[e4];
            a += v.x * wrow[4*e4] + v.y * wrow[4*e4+1] + v.z * wrow[4*e4+2] + v.w * wrow[4*e4+3];
        }
        acc[i] = a;
    }
    __syncthreads();
    #pragma unroll
    for (int i = 0; i < 32; ++i) {
        const int p = p0 + (i << 1);
        stile[p][d] = acc[i];
    }
    __syncthreads();
    {
        const int p = t & 63;
        const int d0 = t >> 6;
        #pragma unroll
        for (int i = 0; i < 32; ++i) {
            const int ch = d0 + (i << 2);
            const float f = (ch < 64) ? spa[ch * NPTS + n0 + p]
                                      : spe[(ch - 64) * NPTS + n0 + p];
            out[(size_t)ch * NPTS + n0 + p] = f + stile[p][ch];
        }
    }
}

extern "C" void kernel_launch(void* const* d_in, const int* in_sizes, int n_in,
                              void* d_out, int out_size, void* d_ws, size_t ws_size,
                              hipStream_t stream) {
    const float* spa = (const float*)d_in[0];
    const float* spe = (const float*)d_in[1];
    const int* idx   = (const int*)d_in[2];
    const float* WQa = (const float*)d_in[3];
    const float* WKa = (const float*)d_in[4];
    const float* WVa = (const float*)d_in[5];
    const float* bVa = (const float*)d_in[6];
    const float* WQe = (const float*)d_in[7];
    const float* WKe = (const float*)d_in[8];
    const float* WVe = (const float*)d_in[9];
    const float* bVe = (const float*)d_in[10];
    float* out = (float*)d_out;

    char* ws = (char*)d_ws;
    unsigned short* featT = (unsigned short*)(ws);              // 16.78 MB bf16 [N][128]
    unsigned short* qeff  = (unsigned short*)(ws + 16777216);   // 16.78 MB bf16 [N][128]
    float* sT   = (float*)(ws + 33554432);                      // 33.55 MB f32 [N][128]
    float* Mmat = (float*)(ws + 67108864);                      // 32 KB f32 [2][64][64]

    k_matM<<<8, 256, 0, stream>>>(WQa, WKa, WQe, WKe, Mmat);
    k_prep<<<1024, 256, 0, stream>>>(spa, spe, Mmat, featT, qeff);
    k_attn<<<16384, 256, 0, stream>>>(featT, qeff, idx, sT);
    k_out<<<1024, 256, 0, stream>>>(sT, spa, spe, WVa, bVa, WVe, bVe, out);
}